// Round 1
// baseline (2557.167 us; speedup 1.0000x reference)
//
#include <hip/hip_runtime.h>
#include <math.h>

#define N_USERS 50000
#define N_ITEMS 30000
#define N_ENTITIES 80000
#define D 64
#define N_KG_EDGES 2000000
#define N_INTERACT 1000000
#define N_ADJ 2000000
#define INV_TEMP 5.0f
#define EPS_PD 1e-6f

__device__ __forceinline__ float wave_reduce_sum(float v) {
    // butterfly over 64 lanes; all lanes end with the sum
    #pragma unroll
    for (int o = 32; o > 0; o >>= 1) v += __shfl_xor(v, o, 64);
    return v;
}

// ---- KG: count incoming edges per head entity ----
__global__ void cnt_kernel(const int* __restrict__ edge_index, float* __restrict__ cnt) {
    int e = blockIdx.x * blockDim.x + threadIdx.x;
    if (e < N_KG_EDGES) atomicAdd(&cnt[edge_index[e]], 1.0f);
}

__global__ void icnt_kernel(float* __restrict__ cnt) {
    int i = blockIdx.x * blockDim.x + threadIdx.x;
    if (i < N_ENTITIES) cnt[i] = 1.0f / fmaxf(cnt[i], 1.0f);
}

// ---- per-user row offsets via binary search (interact_rows sorted) ----
__global__ void rowstart_kernel(const int* __restrict__ rows, int* __restrict__ rowstart) {
    int r = blockIdx.x * blockDim.x + threadIdx.x;
    if (r > N_USERS) return;
    int lo = 0, hi = N_INTERACT;
    while (lo < hi) {
        int mid = (lo + hi) >> 1;
        if (rows[mid] < r) lo = mid + 1; else hi = mid;
    }
    rowstart[r] = lo;
}

// ---- KG scatter: B[head] += A[tail]  (raw sum; /cnt folded downstream) ----
__global__ void kg_scatter(const int* __restrict__ edge_index,
                           const float* __restrict__ A, float* __restrict__ B) {
    unsigned gid = blockIdx.x * blockDim.x + threadIdx.x;
    unsigned e = gid >> 6;
    unsigned d = gid & 63u;
    if (e >= N_KG_EDGES) return;
    int h = edge_index[e];
    int t = edge_index[N_KG_EDGES + e];
    atomicAdd(&B[(unsigned)h * D + d], A[(unsigned)t * D + d]);
}

// ---- e = normalize(B) (cnt cancels under normalize); e_res += e; Anew = e ----
__global__ void entity_norm(const float* __restrict__ B, float* __restrict__ Anew,
                            float* __restrict__ ER) {
    unsigned gid = blockIdx.x * blockDim.x + threadIdx.x;
    unsigned i = gid >> 6;
    if (i >= N_ENTITIES) return;
    float x = B[gid];
    float ss = wave_reduce_sum(x * x);
    float nrm = fmaxf(sqrtf(ss), 1e-12f);
    float e = x / nrm;
    Anew[gid] = e;
    ER[gid] += e;
}

// ---- full per-user pipeline, one wave per user, lane = dim ----
// item_agg[c] = icnt[c] * B[c]
__global__ void user_hop(const float* __restrict__ B, const float* __restrict__ icnt,
                         const int* __restrict__ rowstart, const int* __restrict__ cols,
                         const float* __restrict__ vals, float* __restrict__ score,
                         float* __restrict__ UR) {
    int wid = (blockIdx.x * blockDim.x + threadIdx.x) >> 6;
    int lane = threadIdx.x & 63;
    if (wid >= N_USERS) return;
    int s = rowstart[wid], t = rowstart[wid + 1];

    // pass A: user_mean (weighted sum), per-lane = per-dim
    float mean = 0.f;
    for (int e = s; e < t; ++e) {
        int c = cols[e];
        mean += vals[e] * icnt[c] * B[c * D + lane];
    }

    // pass B: per-edge score = ||item_agg[c] - mean + eps|| / TEMP, track max
    float m = -INFINITY;
    for (int e = s; e < t; ++e) {
        int c = cols[e];
        float dl = icnt[c] * B[c * D + lane] - mean + EPS_PD;
        float ss = wave_reduce_sum(dl * dl);
        float sc = sqrtf(ss) * INV_TEMP;
        if (lane == 0) score[e] = sc;
        m = fmaxf(m, sc);
    }
    __threadfence_block();  // order lane0's score stores before wave reloads

    // pass C: softmax denominator
    float denom = 0.f;
    for (int e = s; e < t; ++e) denom += __expf(score[e] - m);
    float inv_denom = denom > 0.f ? 1.0f / denom : 0.f;

    // pass D: user_agg = sum att * item_agg[c]
    float acc = 0.f;
    for (int e = s; e < t; ++e) {
        int c = cols[e];
        float w = __expf(score[e] - m) * inv_denom;
        acc += w * icnt[c] * B[c * D + lane];
    }

    // u = normalize(user_agg); u_res += u
    float ss = wave_reduce_sum(acc * acc);
    float nrm = fmaxf(sqrtf(ss), 1e-12f);
    UR[wid * D + lane] += acc / nrm;
}

// ---- adj SpMM scatter: Y[row] += val * X[col] ----
__global__ void adj_scatter(const int* __restrict__ rows, const int* __restrict__ cols,
                            const float* __restrict__ vals, const float* __restrict__ X,
                            float* __restrict__ Y) {
    unsigned gid = blockIdx.x * blockDim.x + threadIdx.x;
    unsigned e = gid >> 6;
    unsigned d = gid & 63u;
    if (e >= N_ADJ) return;
    int r = rows[e], c = cols[e];
    atomicAdd(&Y[(unsigned)r * D + d], vals[e] * X[(unsigned)c * D + d]);
}

__global__ void add_kernel(float* __restrict__ out, const float* __restrict__ src, int n) {
    int i = blockIdx.x * blockDim.x + threadIdx.x;
    if (i < n) out[i] += src[i];
}

__global__ void add_scale_kernel(float* __restrict__ out, const float* __restrict__ src,
                                 float sc, int n) {
    int i = blockIdx.x * blockDim.x + threadIdx.x;
    if (i < n) out[i] = (out[i] + src[i]) * sc;
}

extern "C" void kernel_launch(void* const* d_in, const int* in_sizes, int n_in,
                              void* d_out, int out_size, void* d_ws, size_t ws_size,
                              hipStream_t stream) {
    const float* all_embed     = (const float*)d_in[0];
    const float* interact_vals = (const float*)d_in[1];
    const float* adj_vals      = (const float*)d_in[2];
    const int*   edge_index    = (const int*)d_in[3];
    // d_in[4] = edge_type (unused by forward)
    const int*   interact_rows = (const int*)d_in[5];
    const int*   interact_cols = (const int*)d_in[6];
    const int*   adj_rows      = (const int*)d_in[7];
    const int*   adj_cols      = (const int*)d_in[8];
    float* out = (float*)d_out;

    const size_t entN = (size_t)N_ENTITIES * D;  // 5,120,000
    const size_t usrN = (size_t)N_USERS * D;     // 3,200,000
    const size_t xN   = (size_t)(N_USERS + N_ITEMS) * D;  // 5,120,000 == out_size

    float* ws    = (float*)d_ws;
    float* A     = ws;                 // entity features (hop input) / later x
    float* B     = A + entN;           // entity_agg (raw sums) / later x1
    float* ER    = B + entN;           // e_res / later x2
    float* UR    = ER + entN;          // u_res
    float* ICNT  = UR + usrN;          // inverse head counts
    float* SCORE = ICNT + N_ENTITIES;  // per-interact-edge score
    int* ROWSTART = (int*)(SCORE + N_INTERACT);  // 50001 ints

    // ---- init ----
    hipMemcpyAsync(UR, all_embed, usrN * sizeof(float), hipMemcpyDeviceToDevice, stream);
    hipMemcpyAsync(A,  all_embed + usrN, entN * sizeof(float), hipMemcpyDeviceToDevice, stream);
    hipMemcpyAsync(ER, all_embed + usrN, entN * sizeof(float), hipMemcpyDeviceToDevice, stream);
    hipMemsetAsync(ICNT, 0, N_ENTITIES * sizeof(float), stream);
    cnt_kernel<<<(N_KG_EDGES + 255) / 256, 256, 0, stream>>>(edge_index, ICNT);
    icnt_kernel<<<(N_ENTITIES + 255) / 256, 256, 0, stream>>>(ICNT);
    rowstart_kernel<<<(N_USERS + 256) / 256, 256, 0, stream>>>(interact_rows, ROWSTART);

    // ---- KG hops ----
    for (int hop = 0; hop < 2; ++hop) {
        hipMemsetAsync(B, 0, entN * sizeof(float), stream);
        kg_scatter<<<(int)(((long long)N_KG_EDGES * 64 + 255) / 256), 256, 0, stream>>>(
            edge_index, A, B);
        user_hop<<<(N_USERS * 64 + 255) / 256, 256, 0, stream>>>(
            B, ICNT, ROWSTART, interact_cols, interact_vals, SCORE, UR);
        entity_norm<<<(int)((entN + 255) / 256), 256, 0, stream>>>(B, A, ER);
    }

    // ---- x = concat(u_res, e_res[:N_ITEMS]); acc = x (in d_out) ----
    hipMemcpyAsync(A, UR, usrN * sizeof(float), hipMemcpyDeviceToDevice, stream);
    hipMemcpyAsync(A + usrN, ER, (size_t)N_ITEMS * D * sizeof(float),
                   hipMemcpyDeviceToDevice, stream);
    hipMemcpyAsync(out, A, xN * sizeof(float), hipMemcpyDeviceToDevice, stream);

    // ---- LGCN layer 1: x1 = adj @ x; acc += x1 ----
    hipMemsetAsync(B, 0, xN * sizeof(float), stream);
    adj_scatter<<<(int)(((long long)N_ADJ * 64 + 255) / 256), 256, 0, stream>>>(
        adj_rows, adj_cols, adj_vals, A, B);
    add_kernel<<<(int)((xN + 255) / 256), 256, 0, stream>>>(out, B, (int)xN);

    // ---- LGCN layer 2: x2 = adj @ x1; out = (acc + x2) / 3 ----
    hipMemsetAsync(ER, 0, xN * sizeof(float), stream);
    adj_scatter<<<(int)(((long long)N_ADJ * 64 + 255) / 256), 256, 0, stream>>>(
        adj_rows, adj_cols, adj_vals, B, ER);
    add_scale_kernel<<<(int)((xN + 255) / 256), 256, 0, stream>>>(
        out, ER, 1.0f / 3.0f, (int)xN);
}

// Round 2
// 1896.563 us; speedup vs baseline: 1.3483x; 1.3483x over previous
//
#include <hip/hip_runtime.h>
#include <math.h>

#define N_USERS 50000
#define N_ITEMS 30000
#define N_ENTITIES 80000
#define N_UI (N_USERS + N_ITEMS)
#define D 64
#define N_KG_EDGES 2000000
#define N_INTERACT 1000000
#define N_ADJ 2000000
#define INV_TEMP 5.0f
#define EPS_PD 1e-6f
#define SCAN_T 1024

__device__ __forceinline__ float wave_reduce_sum(float v) {
    #pragma unroll
    for (int o = 32; o > 0; o >>= 1) v += __shfl_xor(v, o, 64);
    return v;
}

// ---- int histogram over keys ----
__global__ void hist_kernel(const int* __restrict__ keys, int* __restrict__ cnt, int n) {
    int e = blockIdx.x * blockDim.x + threadIdx.x;
    if (e < n) atomicAdd(&cnt[keys[e]], 1);
}

// ---- icnt = 1/max(cnt,1) from int counts ----
__global__ void icnt_kernel(const int* __restrict__ cnt, float* __restrict__ icnt) {
    int i = blockIdx.x * blockDim.x + threadIdx.x;
    if (i < N_ENTITIES) icnt[i] = 1.0f / fmaxf((float)cnt[i], 1.0f);
}

// ---- single-block exclusive scan: rowptr[0]=0, rowptr[i+1]=incl_prefix(cnt,i) ----
__global__ void scan_kernel(const int* __restrict__ cnt, int* __restrict__ rowptr, int n) {
    __shared__ int tmp[SCAN_T];
    __shared__ int carry_s;
    if (threadIdx.x == 0) { carry_s = 0; rowptr[0] = 0; }
    __syncthreads();
    for (int base = 0; base < n; base += SCAN_T) {
        int i = base + threadIdx.x;
        int v = (i < n) ? cnt[i] : 0;
        tmp[threadIdx.x] = v;
        __syncthreads();
        for (int o = 1; o < SCAN_T; o <<= 1) {
            int t = (threadIdx.x >= o) ? tmp[threadIdx.x - o] : 0;
            __syncthreads();
            tmp[threadIdx.x] += t;
            __syncthreads();
        }
        int incl = tmp[threadIdx.x];
        int carry = carry_s;
        if (i < n) rowptr[i + 1] = carry + incl;
        __syncthreads();
        if (threadIdx.x == SCAN_T - 1) carry_s = carry + incl;
        __syncthreads();
    }
}

// ---- KG fill: bucket tails by head ----
__global__ void kg_fill(const int* __restrict__ edge_index, int* __restrict__ pos,
                        int* __restrict__ tails) {
    int e = blockIdx.x * blockDim.x + threadIdx.x;
    if (e >= N_KG_EDGES) return;
    int h = edge_index[e];
    int slot = atomicAdd(&pos[h], 1);
    tails[slot] = edge_index[N_KG_EDGES + e];
}

// ---- adj fill: bucket (col,val) by row ----
__global__ void adj_fill(const int* __restrict__ rows, const int* __restrict__ cols,
                         const float* __restrict__ vals, int* __restrict__ pos,
                         int* __restrict__ col_out, float* __restrict__ val_out) {
    int e = blockIdx.x * blockDim.x + threadIdx.x;
    if (e >= N_ADJ) return;
    int r = rows[e];
    int slot = atomicAdd(&pos[r], 1);
    col_out[slot] = cols[e];
    val_out[slot] = vals[e];
}

// ---- per-user row offsets via binary search (interact_rows sorted) ----
__global__ void rowstart_kernel(const int* __restrict__ rows, int* __restrict__ rowstart) {
    int r = blockIdx.x * blockDim.x + threadIdx.x;
    if (r > N_USERS) return;
    int lo = 0, hi = N_INTERACT;
    while (lo < hi) {
        int mid = (lo + hi) >> 1;
        if (rows[mid] < r) lo = mid + 1; else hi = mid;
    }
    rowstart[r] = lo;
}

// ---- KG gather SpMM: B[i] = sum_{e in row i} A[tail[e]]  (raw sum) ----
__global__ void kg_gather(const int* __restrict__ rowptr, const int* __restrict__ tails,
                          const float* __restrict__ A, float* __restrict__ B) {
    int wid = (blockIdx.x * blockDim.x + threadIdx.x) >> 6;
    int lane = threadIdx.x & 63;
    if (wid >= N_ENTITIES) return;
    int s = rowptr[wid], t = rowptr[wid + 1];
    float acc = 0.f;
    for (int e = s; e < t; ++e)
        acc += A[(unsigned)tails[e] * D + lane];
    B[(unsigned)wid * D + lane] = acc;
}

// ---- e = normalize(B) (cnt cancels under normalize); e_res += e; Anew = e ----
__global__ void entity_norm(const float* __restrict__ B, float* __restrict__ Anew,
                            float* __restrict__ ER) {
    unsigned gid = blockIdx.x * blockDim.x + threadIdx.x;
    unsigned i = gid >> 6;
    if (i >= N_ENTITIES) return;
    float x = B[gid];
    float ss = wave_reduce_sum(x * x);
    float nrm = fmaxf(sqrtf(ss), 1e-12f);
    float e = x / nrm;
    Anew[gid] = e;
    ER[gid] += e;
}

// ---- per-user pipeline: mean pass + online-softmax fused pass ----
__global__ void user_hop(const float* __restrict__ B, const float* __restrict__ icnt,
                         const int* __restrict__ rowstart, const int* __restrict__ cols,
                         const float* __restrict__ vals, float* __restrict__ UR) {
    int wid = (blockIdx.x * blockDim.x + threadIdx.x) >> 6;
    int lane = threadIdx.x & 63;
    if (wid >= N_USERS) return;
    int s = rowstart[wid], t = rowstart[wid + 1];

    // pass A: user_mean (weighted sum), per-lane = per-dim
    float mean = 0.f;
    for (int e = s; e < t; ++e) {
        int c = cols[e];
        mean += vals[e] * icnt[c] * B[c * D + lane];
    }

    // pass B: online softmax — score, running max, rescaled denom + weighted sum
    float m = -INFINITY, denom = 0.f, acc = 0.f;
    for (int e = s; e < t; ++e) {
        int c = cols[e];
        float item_l = icnt[c] * B[c * D + lane];
        float dl = item_l - mean + EPS_PD;
        float ss = wave_reduce_sum(dl * dl);
        float sc = sqrtf(ss) * INV_TEMP;     // uniform across the wave
        float m_new = fmaxf(m, sc);
        float scale = __expf(m - m_new);     // exp(-inf)=0 handles first edge
        float ex = __expf(sc - m_new);
        denom = denom * scale + ex;
        acc = acc * scale + ex * item_l;
        m = m_new;
    }
    float inv_denom = denom > 0.f ? 1.0f / denom : 0.f;
    acc *= inv_denom;

    float ss = wave_reduce_sum(acc * acc);
    float nrm = fmaxf(sqrtf(ss), 1e-12f);
    UR[wid * D + lane] += acc / nrm;
}

// ---- adj gather SpMM with fused epilogue ----
// MODE 0: Y[g] = s; out[g] = Xadd[g] + s        (layer 1: x1 = adj@x; acc = x + x1)
// MODE 1: out[g] = (out[g] + s) / 3             (layer 2: out = (acc + adj@x1)/3)
template <int MODE>
__global__ void adj_spmm(const int* __restrict__ rowptr, const int* __restrict__ cols,
                         const float* __restrict__ vals, const float* __restrict__ X,
                         const float* __restrict__ Xadd, float* __restrict__ Y,
                         float* __restrict__ out) {
    int wid = (blockIdx.x * blockDim.x + threadIdx.x) >> 6;
    int lane = threadIdx.x & 63;
    if (wid >= N_UI) return;
    int s = rowptr[wid], t = rowptr[wid + 1];
    float acc = 0.f;
    for (int e = s; e < t; ++e)
        acc += vals[e] * X[(unsigned)cols[e] * D + lane];
    unsigned g = (unsigned)wid * D + lane;
    if (MODE == 0) { Y[g] = acc; out[g] = Xadd[g] + acc; }
    else           { out[g] = (out[g] + acc) * (1.0f / 3.0f); }
}

extern "C" void kernel_launch(void* const* d_in, const int* in_sizes, int n_in,
                              void* d_out, int out_size, void* d_ws, size_t ws_size,
                              hipStream_t stream) {
    const float* all_embed     = (const float*)d_in[0];
    const float* interact_vals = (const float*)d_in[1];
    const float* adj_vals      = (const float*)d_in[2];
    const int*   edge_index    = (const int*)d_in[3];
    // d_in[4] = edge_type (unused by forward)
    const int*   interact_rows = (const int*)d_in[5];
    const int*   interact_cols = (const int*)d_in[6];
    const int*   adj_rows      = (const int*)d_in[7];
    const int*   adj_cols      = (const int*)d_in[8];
    float* out = (float*)d_out;

    const size_t entN = (size_t)N_ENTITIES * D;  // 5,120,000
    const size_t usrN = (size_t)N_USERS * D;     // 3,200,000

    float* ws   = (float*)d_ws;
    float* A    = ws;                 // entity features (hop input) / later x
    float* B    = A + entN;           // entity_agg raw sums / later x1
    float* ER   = B + entN;           // e_res; after out-assembly reused for adj CSR
    float* UR   = ER + entN;          // u_res
    float* ICNT = UR + usrN;          // inverse head counts (float)
    int* KG_CNT    = (int*)(ICNT + N_ENTITIES);
    int* KG_ROWPTR = KG_CNT + N_ENTITIES;        // N_ENTITIES+1
    int* KG_POS    = KG_ROWPTR + N_ENTITIES + 1;
    int* KG_TAIL   = KG_POS + N_ENTITIES;        // N_KG_EDGES
    int* ROWSTART  = KG_TAIL + N_KG_EDGES;       // N_USERS+1

    // adj CSR overlaid on ER (free after out assembly): needs 4.24M words < 5.12M
    int*   ADJ_CNT    = (int*)ER;
    int*   ADJ_ROWPTR = ADJ_CNT + N_UI;          // N_UI+1
    int*   ADJ_POS    = ADJ_ROWPTR + N_UI + 1;
    int*   ADJ_COL    = ADJ_POS + N_UI;          // N_ADJ
    float* ADJ_VAL    = (float*)(ADJ_COL + N_ADJ);

    // ---- KG CSR build + init ----
    hipMemsetAsync(KG_CNT, 0, N_ENTITIES * sizeof(int), stream);
    hist_kernel<<<(N_KG_EDGES + 255) / 256, 256, 0, stream>>>(edge_index, KG_CNT, N_KG_EDGES);
    icnt_kernel<<<(N_ENTITIES + 255) / 256, 256, 0, stream>>>(KG_CNT, ICNT);
    scan_kernel<<<1, SCAN_T, 0, stream>>>(KG_CNT, KG_ROWPTR, N_ENTITIES);
    hipMemcpyAsync(KG_POS, KG_ROWPTR, N_ENTITIES * sizeof(int),
                   hipMemcpyDeviceToDevice, stream);
    kg_fill<<<(N_KG_EDGES + 255) / 256, 256, 0, stream>>>(edge_index, KG_POS, KG_TAIL);
    rowstart_kernel<<<(N_USERS + 256) / 256, 256, 0, stream>>>(interact_rows, ROWSTART);

    hipMemcpyAsync(UR, all_embed, usrN * sizeof(float), hipMemcpyDeviceToDevice, stream);
    hipMemcpyAsync(A,  all_embed + usrN, entN * sizeof(float), hipMemcpyDeviceToDevice, stream);
    hipMemcpyAsync(ER, all_embed + usrN, entN * sizeof(float), hipMemcpyDeviceToDevice, stream);

    // ---- KG hops ----
    for (int hop = 0; hop < 2; ++hop) {
        kg_gather<<<N_ENTITIES / 4, 256, 0, stream>>>(KG_ROWPTR, KG_TAIL, A, B);
        user_hop<<<N_USERS / 4, 256, 0, stream>>>(B, ICNT, ROWSTART, interact_cols,
                                                  interact_vals, UR);
        entity_norm<<<(int)(entN / 256), 256, 0, stream>>>(B, A, ER);
    }

    // ---- assemble x into A: concat(u_res, e_res[:N_ITEMS]) ----
    hipMemcpyAsync(A, UR, usrN * sizeof(float), hipMemcpyDeviceToDevice, stream);
    hipMemcpyAsync(A + usrN, ER, (size_t)N_ITEMS * D * sizeof(float),
                   hipMemcpyDeviceToDevice, stream);

    // ---- adj CSR build (ER now free) ----
    hipMemsetAsync(ADJ_CNT, 0, N_UI * sizeof(int), stream);
    hist_kernel<<<(N_ADJ + 255) / 256, 256, 0, stream>>>(adj_rows, ADJ_CNT, N_ADJ);
    scan_kernel<<<1, SCAN_T, 0, stream>>>(ADJ_CNT, ADJ_ROWPTR, N_UI);
    hipMemcpyAsync(ADJ_POS, ADJ_ROWPTR, N_UI * sizeof(int),
                   hipMemcpyDeviceToDevice, stream);
    adj_fill<<<(N_ADJ + 255) / 256, 256, 0, stream>>>(adj_rows, adj_cols, adj_vals,
                                                      ADJ_POS, ADJ_COL, ADJ_VAL);

    // ---- LGCN layer 1: x1 = adj@x (B); out = x + x1 ----
    adj_spmm<0><<<N_UI / 4, 256, 0, stream>>>(ADJ_ROWPTR, ADJ_COL, ADJ_VAL, A, A, B, out);
    // ---- LGCN layer 2: out = (out + adj@x1) / 3 ----
    adj_spmm<1><<<N_UI / 4, 256, 0, stream>>>(ADJ_ROWPTR, ADJ_COL, ADJ_VAL, B, nullptr,
                                              nullptr, out);
}

// Round 3
// 1094.368 us; speedup vs baseline: 2.3367x; 1.7330x over previous
//
#include <hip/hip_runtime.h>
#include <math.h>

#define N_USERS 50000
#define N_ITEMS 30000
#define N_ENTITIES 80000
#define N_UI (N_USERS + N_ITEMS)
#define D 64
#define N_KG_EDGES 2000000
#define N_INTERACT 1000000
#define N_ADJ 2000000
#define INV_TEMP 5.0f
#define EPS_PD 1e-6f
#define SCAN_T 1024

// ---- int histogram over keys ----
__global__ void hist_kernel(const int* __restrict__ keys, int* __restrict__ cnt, int n) {
    int e = blockIdx.x * blockDim.x + threadIdx.x;
    if (e < n) atomicAdd(&cnt[keys[e]], 1);
}

// ---- icnt = 1/max(cnt,1) ----
__global__ void icnt_kernel(const int* __restrict__ cnt, float* __restrict__ icnt) {
    int i = blockIdx.x * blockDim.x + threadIdx.x;
    if (i < N_ENTITIES) icnt[i] = 1.0f / fmaxf((float)cnt[i], 1.0f);
}

// ---- single-block scan, shfl-based (4 barriers per 1024-chunk) ----
__global__ void scan_kernel(const int* __restrict__ cnt, int* __restrict__ rowptr, int n) {
    __shared__ int wpart[16];
    __shared__ int carry_s;
    int lane = threadIdx.x & 63;
    int wv = threadIdx.x >> 6;
    if (threadIdx.x == 0) { carry_s = 0; rowptr[0] = 0; }
    __syncthreads();
    for (int base = 0; base < n; base += SCAN_T) {
        int i = base + threadIdx.x;
        int x = (i < n) ? cnt[i] : 0;
        #pragma unroll
        for (int o = 1; o < 64; o <<= 1) {
            int t = __shfl_up(x, o, 64);
            if (lane >= o) x += t;
        }
        if (lane == 63) wpart[wv] = x;
        __syncthreads();
        if (wv == 0) {
            int p = (lane < 16) ? wpart[lane] : 0;
            #pragma unroll
            for (int o = 1; o < 16; o <<= 1) {
                int t = __shfl_up(p, o, 64);
                if (lane >= o) p += t;
            }
            if (lane < 16) wpart[lane] = p;
        }
        __syncthreads();
        int add = carry_s + (wv > 0 ? wpart[wv - 1] : 0);
        if (i < n) rowptr[i + 1] = x + add;
        __syncthreads();
        if (threadIdx.x == SCAN_T - 1) carry_s = x + add;
        __syncthreads();
    }
}

// ---- KG fill: bucket tails by head ----
__global__ void kg_fill(const int* __restrict__ edge_index, int* __restrict__ pos,
                        int* __restrict__ tails) {
    int e = blockIdx.x * blockDim.x + threadIdx.x;
    if (e >= N_KG_EDGES) return;
    int h = edge_index[e];
    int slot = atomicAdd(&pos[h], 1);
    tails[slot] = edge_index[N_KG_EDGES + e];
}

// ---- adj fill: bucket fused (col, val) 8B pairs by row ----
__global__ void adj_fill(const int* __restrict__ rows, const int* __restrict__ cols,
                         const float* __restrict__ vals, int* __restrict__ pos,
                         int2* __restrict__ pair) {
    int e = blockIdx.x * blockDim.x + threadIdx.x;
    if (e >= N_ADJ) return;
    int r = rows[e];
    int slot = atomicAdd(&pos[r], 1);
    pair[slot] = make_int2(cols[e], __float_as_int(vals[e]));
}

// ---- per-user row offsets via binary search (interact_rows sorted) ----
__global__ void rowstart_kernel(const int* __restrict__ rows, int* __restrict__ rowstart) {
    int r = blockIdx.x * blockDim.x + threadIdx.x;
    if (r > N_USERS) return;
    int lo = 0, hi = N_INTERACT;
    while (lo < hi) {
        int mid = (lo + hi) >> 1;
        if (rows[mid] < r) lo = mid + 1; else hi = mid;
    }
    rowstart[r] = lo;
}

// ---- KG hop, fused: raw gather-sum + normalize + e_res accumulate + SNORM ----
// 4 groups x 16 lanes; group = edge stream, lane = 4 dims (float4)
__global__ void kg_hop(const int* __restrict__ rowptr, const int* __restrict__ tails,
                       const float* __restrict__ icnt, const float* __restrict__ Ain,
                       float* __restrict__ Aout, float* __restrict__ ER,
                       float* __restrict__ snorm) {
    int wid = (blockIdx.x * blockDim.x + threadIdx.x) >> 6;
    int lane = threadIdx.x & 63;
    int g = lane >> 4, gl = lane & 15;
    if (wid >= N_ENTITIES) return;
    int s = rowptr[wid], t = rowptr[wid + 1];
    float4 acc = {0.f, 0.f, 0.f, 0.f};
    int e = s + g;
    if (e < t) {
        int c = tails[e];
        while (true) {
            int e2 = e + 4;
            int c2 = (e2 < t) ? tails[e2] : 0;   // prefetch next index
            const float4 r = *(const float4*)(Ain + (size_t)c * D + gl * 4);
            acc.x += r.x; acc.y += r.y; acc.z += r.z; acc.w += r.w;
            if (e2 >= t) break;
            e = e2; c = c2;
        }
    }
    // cross-group sum (xor 16, 32)
    acc.x += __shfl_xor(acc.x, 16, 64); acc.x += __shfl_xor(acc.x, 32, 64);
    acc.y += __shfl_xor(acc.y, 16, 64); acc.y += __shfl_xor(acc.y, 32, 64);
    acc.z += __shfl_xor(acc.z, 16, 64); acc.z += __shfl_xor(acc.z, 32, 64);
    acc.w += __shfl_xor(acc.w, 16, 64); acc.w += __shfl_xor(acc.w, 32, 64);
    // row norm: per-lane dot4 + 16-lane reduce
    float ss = acc.x * acc.x + acc.y * acc.y + acc.z * acc.z + acc.w * acc.w;
    ss += __shfl_xor(ss, 1, 64); ss += __shfl_xor(ss, 2, 64);
    ss += __shfl_xor(ss, 4, 64); ss += __shfl_xor(ss, 8, 64);
    float nrm = fmaxf(sqrtf(ss), 1e-12f);
    float inv = 1.0f / nrm;
    if (g == 0) {
        size_t o = (size_t)wid * D + gl * 4;
        float4 ev = {acc.x * inv, acc.y * inv, acc.z * inv, acc.w * inv};
        *(float4*)(Aout + o) = ev;
        float4 er = *(const float4*)(ER + o);
        er.x += ev.x; er.y += ev.y; er.z += ev.z; er.w += ev.w;
        *(float4*)(ER + o) = er;
        // item_agg[i] = e_row[i] * (||raw||*icnt[i]) reconstructs raw*icnt
        if (wid < N_ITEMS && gl == 0) snorm[wid] = nrm * icnt[wid];
    }
}

// ---- per-user pipeline: mean pass + 4 independent online-softmax chains ----
__global__ void user_hop(const float* __restrict__ E, const float* __restrict__ snorm,
                         const int* __restrict__ rowstart, const int* __restrict__ cols,
                         const float* __restrict__ vals, float* __restrict__ UR) {
    int wid = (blockIdx.x * blockDim.x + threadIdx.x) >> 6;
    int lane = threadIdx.x & 63;
    int g = lane >> 4, gl = lane & 15;
    if (wid >= N_USERS) return;
    int s = rowstart[wid], t = rowstart[wid + 1];

    // pass A: user_mean (weighted), per-group partials then cross-group sum
    float4 mean = {0.f, 0.f, 0.f, 0.f};
    for (int e = s + g; e < t; e += 4) {
        int c = cols[e];
        float w = vals[e] * snorm[c];
        const float4 r = *(const float4*)(E + (size_t)c * D + gl * 4);
        mean.x += w * r.x; mean.y += w * r.y; mean.z += w * r.z; mean.w += w * r.w;
    }
    mean.x += __shfl_xor(mean.x, 16, 64); mean.x += __shfl_xor(mean.x, 32, 64);
    mean.y += __shfl_xor(mean.y, 16, 64); mean.y += __shfl_xor(mean.y, 32, 64);
    mean.z += __shfl_xor(mean.z, 16, 64); mean.z += __shfl_xor(mean.z, 32, 64);
    mean.w += __shfl_xor(mean.w, 16, 64); mean.w += __shfl_xor(mean.w, 32, 64);

    // pass B: per-group online softmax (independent chains)
    float m = -INFINITY, denom = 0.f;
    float4 acc = {0.f, 0.f, 0.f, 0.f};
    for (int e = s + g; e < t; e += 4) {
        int c = cols[e];
        float sn = snorm[c];
        const float4 r = *(const float4*)(E + (size_t)c * D + gl * 4);
        float4 il = {sn * r.x, sn * r.y, sn * r.z, sn * r.w};
        float dx = il.x - mean.x + EPS_PD;
        float dy = il.y - mean.y + EPS_PD;
        float dz = il.z - mean.z + EPS_PD;
        float dw = il.w - mean.w + EPS_PD;
        float ssl = dx * dx + dy * dy + dz * dz + dw * dw;
        ssl += __shfl_xor(ssl, 1, 64); ssl += __shfl_xor(ssl, 2, 64);
        ssl += __shfl_xor(ssl, 4, 64); ssl += __shfl_xor(ssl, 8, 64);
        float sc = sqrtf(ssl) * INV_TEMP;          // uniform within group
        float m_new = fmaxf(m, sc);
        float scale = __expf(m - m_new);           // first edge: exp(-inf)=0
        float ex = __expf(sc - m_new);
        denom = denom * scale + ex;
        acc.x = acc.x * scale + ex * il.x;
        acc.y = acc.y * scale + ex * il.y;
        acc.z = acc.z * scale + ex * il.z;
        acc.w = acc.w * scale + ex * il.w;
        m = m_new;
    }
    // merge 4 group states
    float mg = fmaxf(m, __shfl_xor(m, 16, 64));
    mg = fmaxf(mg, __shfl_xor(mg, 32, 64));
    float scl = __expf(fmaxf(m - mg, -88.0f));     // fmax eats NaN from (-inf)-(-inf)
    denom *= scl;
    acc.x *= scl; acc.y *= scl; acc.z *= scl; acc.w *= scl;
    denom += __shfl_xor(denom, 16, 64); denom += __shfl_xor(denom, 32, 64);
    acc.x += __shfl_xor(acc.x, 16, 64); acc.x += __shfl_xor(acc.x, 32, 64);
    acc.y += __shfl_xor(acc.y, 16, 64); acc.y += __shfl_xor(acc.y, 32, 64);
    acc.z += __shfl_xor(acc.z, 16, 64); acc.z += __shfl_xor(acc.z, 32, 64);
    acc.w += __shfl_xor(acc.w, 16, 64); acc.w += __shfl_xor(acc.w, 32, 64);
    float invd = denom > 0.f ? 1.0f / denom : 0.f;
    acc.x *= invd; acc.y *= invd; acc.z *= invd; acc.w *= invd;
    // normalize + accumulate
    float ss = acc.x * acc.x + acc.y * acc.y + acc.z * acc.z + acc.w * acc.w;
    ss += __shfl_xor(ss, 1, 64); ss += __shfl_xor(ss, 2, 64);
    ss += __shfl_xor(ss, 4, 64); ss += __shfl_xor(ss, 8, 64);
    float inv = 1.0f / fmaxf(sqrtf(ss), 1e-12f);
    if (g == 0) {
        size_t o = (size_t)wid * D + gl * 4;
        float4 u = *(const float4*)(UR + o);
        u.x += acc.x * inv; u.y += acc.y * inv; u.z += acc.z * inv; u.w += acc.w * inv;
        *(float4*)(UR + o) = u;
    }
}

// ---- adj gather SpMM with fused epilogue ----
// MODE 0: Y = adj@X; out = Xadd + Y     MODE 1: out = (out + adj@X) / 3
template <int MODE>
__global__ void adj_spmm(const int* __restrict__ rowptr, const int2* __restrict__ pair,
                         const float* __restrict__ X, const float* __restrict__ Xadd,
                         float* __restrict__ Y, float* __restrict__ out) {
    int wid = (blockIdx.x * blockDim.x + threadIdx.x) >> 6;
    int lane = threadIdx.x & 63;
    int g = lane >> 4, gl = lane & 15;
    if (wid >= N_UI) return;
    int s = rowptr[wid], t = rowptr[wid + 1];
    float4 acc = {0.f, 0.f, 0.f, 0.f};
    int e = s + g;
    if (e < t) {
        int2 p = pair[e];
        while (true) {
            int e2 = e + 4;
            int2 p2 = (e2 < t) ? pair[e2] : make_int2(0, 0);  // prefetch
            const float4 r = *(const float4*)(X + (size_t)p.x * D + gl * 4);
            float v = __int_as_float(p.y);
            acc.x += v * r.x; acc.y += v * r.y; acc.z += v * r.z; acc.w += v * r.w;
            if (e2 >= t) break;
            e = e2; p = p2;
        }
    }
    acc.x += __shfl_xor(acc.x, 16, 64); acc.x += __shfl_xor(acc.x, 32, 64);
    acc.y += __shfl_xor(acc.y, 16, 64); acc.y += __shfl_xor(acc.y, 32, 64);
    acc.z += __shfl_xor(acc.z, 16, 64); acc.z += __shfl_xor(acc.z, 32, 64);
    acc.w += __shfl_xor(acc.w, 16, 64); acc.w += __shfl_xor(acc.w, 32, 64);
    if (g == 0) {
        size_t o = (size_t)wid * D + gl * 4;
        if (MODE == 0) {
            *(float4*)(Y + o) = acc;
            const float4 xa = *(const float4*)(Xadd + o);
            float4 ov = {xa.x + acc.x, xa.y + acc.y, xa.z + acc.z, xa.w + acc.w};
            *(float4*)(out + o) = ov;
        } else {
            float4 ov = *(const float4*)(out + o);
            ov.x = (ov.x + acc.x) * (1.0f / 3.0f);
            ov.y = (ov.y + acc.y) * (1.0f / 3.0f);
            ov.z = (ov.z + acc.z) * (1.0f / 3.0f);
            ov.w = (ov.w + acc.w) * (1.0f / 3.0f);
            *(float4*)(out + o) = ov;
        }
    }
}

extern "C" void kernel_launch(void* const* d_in, const int* in_sizes, int n_in,
                              void* d_out, int out_size, void* d_ws, size_t ws_size,
                              hipStream_t stream) {
    const float* all_embed     = (const float*)d_in[0];
    const float* interact_vals = (const float*)d_in[1];
    const float* adj_vals      = (const float*)d_in[2];
    const int*   edge_index    = (const int*)d_in[3];
    // d_in[4] = edge_type (unused)
    const int*   interact_rows = (const int*)d_in[5];
    const int*   interact_cols = (const int*)d_in[6];
    const int*   adj_rows      = (const int*)d_in[7];
    const int*   adj_cols      = (const int*)d_in[8];
    float* out = (float*)d_out;

    const size_t entN = (size_t)N_ENTITIES * D;   // 5,120,000
    const size_t usrN = (size_t)N_USERS * D;      // 3,200,000
    const size_t itmN = (size_t)N_ITEMS * D;      // 1,920,000

    float* ws    = (float*)d_ws;
    float* A0    = ws;                  // entity features ping
    float* A1    = A0 + entN;           // entity features pong / later x
    float* ER    = A1 + entN;           // e_res; after x-assembly: adj CSR overlay
    float* UR    = ER + entN;           // u_res
    float* ICNT  = UR + usrN;           // inverse head counts
    float* SNORM = ICNT + N_ENTITIES;   // per-item ||raw||*icnt (N_ITEMS)
    int* KG_CNT    = (int*)(SNORM + N_ITEMS);
    int* KG_ROWPTR = KG_CNT + N_ENTITIES;          // N_ENTITIES+1 (+pad)
    int* KG_POS    = KG_ROWPTR + N_ENTITIES + 2;
    int* KG_TAIL   = KG_POS + N_ENTITIES;          // N_KG_EDGES
    int* ROWSTART  = KG_TAIL + N_KG_EDGES;         // N_USERS+1

    // adj CSR overlaid on ER (free after x assembled into A1)
    int*  ADJ_CNT    = (int*)ER;
    int*  ADJ_ROWPTR = ADJ_CNT + N_UI;             // N_UI+1 (+pad to even)
    int*  ADJ_POS    = ADJ_ROWPTR + N_UI + 2;
    int2* ADJ_PAIR   = (int2*)(ADJ_POS + N_UI);    // word off 240002 (8B-aligned)

    // ---- KG CSR build + init ----
    hipMemsetAsync(KG_CNT, 0, N_ENTITIES * sizeof(int), stream);
    hist_kernel<<<(N_KG_EDGES + 255) / 256, 256, 0, stream>>>(edge_index, KG_CNT, N_KG_EDGES);
    icnt_kernel<<<(N_ENTITIES + 255) / 256, 256, 0, stream>>>(KG_CNT, ICNT);
    scan_kernel<<<1, SCAN_T, 0, stream>>>(KG_CNT, KG_ROWPTR, N_ENTITIES);
    hipMemcpyAsync(KG_POS, KG_ROWPTR, N_ENTITIES * sizeof(int),
                   hipMemcpyDeviceToDevice, stream);
    kg_fill<<<(N_KG_EDGES + 255) / 256, 256, 0, stream>>>(edge_index, KG_POS, KG_TAIL);
    rowstart_kernel<<<(N_USERS + 256) / 256, 256, 0, stream>>>(interact_rows, ROWSTART);

    hipMemcpyAsync(UR, all_embed, usrN * sizeof(float), hipMemcpyDeviceToDevice, stream);
    hipMemcpyAsync(A0, all_embed + usrN, entN * sizeof(float), hipMemcpyDeviceToDevice, stream);
    hipMemcpyAsync(ER, all_embed + usrN, entN * sizeof(float), hipMemcpyDeviceToDevice, stream);

    // ---- KG hops (entity_norm fused into kg_hop) ----
    kg_hop<<<N_ENTITIES / 4, 256, 0, stream>>>(KG_ROWPTR, KG_TAIL, ICNT, A0, A1, ER, SNORM);
    user_hop<<<N_USERS / 4, 256, 0, stream>>>(A1, SNORM, ROWSTART, interact_cols,
                                              interact_vals, UR);
    kg_hop<<<N_ENTITIES / 4, 256, 0, stream>>>(KG_ROWPTR, KG_TAIL, ICNT, A1, A0, ER, SNORM);
    user_hop<<<N_USERS / 4, 256, 0, stream>>>(A0, SNORM, ROWSTART, interact_cols,
                                              interact_vals, UR);

    // ---- assemble x into A1: concat(u_res, e_res[:N_ITEMS]) ----
    hipMemcpyAsync(A1, UR, usrN * sizeof(float), hipMemcpyDeviceToDevice, stream);
    hipMemcpyAsync(A1 + usrN, ER, itmN * sizeof(float), hipMemcpyDeviceToDevice, stream);

    // ---- adj CSR build (ER region now free) ----
    hipMemsetAsync(ADJ_CNT, 0, N_UI * sizeof(int), stream);
    hist_kernel<<<(N_ADJ + 255) / 256, 256, 0, stream>>>(adj_rows, ADJ_CNT, N_ADJ);
    scan_kernel<<<1, SCAN_T, 0, stream>>>(ADJ_CNT, ADJ_ROWPTR, N_UI);
    hipMemcpyAsync(ADJ_POS, ADJ_ROWPTR, N_UI * sizeof(int),
                   hipMemcpyDeviceToDevice, stream);
    adj_fill<<<(N_ADJ + 255) / 256, 256, 0, stream>>>(adj_rows, adj_cols, adj_vals,
                                                      ADJ_POS, ADJ_PAIR);

    // ---- LGCN: x1 = adj@x (A0); out = x + x1; then out = (out + adj@x1)/3 ----
    adj_spmm<0><<<N_UI / 4, 256, 0, stream>>>(ADJ_ROWPTR, ADJ_PAIR, A1, A1, A0, out);
    adj_spmm<1><<<N_UI / 4, 256, 0, stream>>>(ADJ_ROWPTR, ADJ_PAIR, A0, nullptr,
                                              nullptr, out);
}

// Round 4
// 938.075 us; speedup vs baseline: 2.7260x; 1.1666x over previous
//
#include <hip/hip_runtime.h>
#include <math.h>

#define N_USERS 50000
#define N_ITEMS 30000
#define N_ENTITIES 80000
#define N_UI (N_USERS + N_ITEMS)
#define D 64
#define N_KG_EDGES 2000000
#define N_INTERACT 1000000
#define N_ADJ 2000000
#define INV_TEMP 5.0f
#define EPS_PD 1e-6f
#define SCAN_T 1024
#define NPASS 8   // = #XCDs; pass = blockIdx.x & 7 so each output slice is XCD-exclusive

// ---- int histogram over keys ----
__global__ void hist_kernel(const int* __restrict__ keys, int* __restrict__ cnt, int n) {
    int e = blockIdx.x * blockDim.x + threadIdx.x;
    if (e < n) atomicAdd(&cnt[keys[e]], 1);
}

// ---- icnt = 1/max(cnt,1) ----
__global__ void icnt_kernel(const int* __restrict__ cnt, float* __restrict__ icnt) {
    int i = blockIdx.x * blockDim.x + threadIdx.x;
    if (i < N_ENTITIES) icnt[i] = 1.0f / fmaxf((float)cnt[i], 1.0f);
}

// ---- single-block scan; writes rowptr (exclusive+1) AND pos (exclusive) ----
__global__ void scan_kernel(const int* __restrict__ cnt, int* __restrict__ rowptr,
                            int* __restrict__ pos, int n) {
    __shared__ int wpart[16];
    __shared__ int carry_s;
    int lane = threadIdx.x & 63;
    int wv = threadIdx.x >> 6;
    if (threadIdx.x == 0) { carry_s = 0; rowptr[0] = 0; }
    __syncthreads();
    for (int base = 0; base < n; base += SCAN_T) {
        int i = base + threadIdx.x;
        int v = (i < n) ? cnt[i] : 0;
        int x = v;
        #pragma unroll
        for (int o = 1; o < 64; o <<= 1) {
            int t = __shfl_up(x, o, 64);
            if (lane >= o) x += t;
        }
        if (lane == 63) wpart[wv] = x;
        __syncthreads();
        if (wv == 0) {
            int p = (lane < 16) ? wpart[lane] : 0;
            #pragma unroll
            for (int o = 1; o < 16; o <<= 1) {
                int t = __shfl_up(p, o, 64);
                if (lane >= o) p += t;
            }
            if (lane < 16) wpart[lane] = p;
        }
        __syncthreads();
        int add = carry_s + (wv > 0 ? wpart[wv - 1] : 0);
        int incl = x + add;
        if (i < n) { rowptr[i + 1] = incl; pos[i] = incl - v; }
        __syncthreads();
        if (threadIdx.x == SCAN_T - 1) carry_s = incl;
        __syncthreads();
    }
}

// ---- KG fill, 8-pass head-sliced: slice p only touched by blocks with idx%8==p ----
__global__ void kg_fill(const int* __restrict__ edge_index, int* __restrict__ pos,
                        int* __restrict__ tails) {
    int pass = blockIdx.x & (NPASS - 1);
    int e = (blockIdx.x >> 3) * blockDim.x + threadIdx.x;
    if (e >= N_KG_EDGES) return;
    int h = edge_index[e];
    if ((unsigned)(h - pass * (N_ENTITIES / NPASS)) >= (unsigned)(N_ENTITIES / NPASS)) return;
    int slot = atomicAdd(&pos[h], 1);
    tails[slot] = edge_index[N_KG_EDGES + e];
}

// ---- adj fill, 8-pass row-sliced, fused (col,val) 8B pairs ----
__global__ void adj_fill(const int* __restrict__ rows, const int* __restrict__ cols,
                         const float* __restrict__ vals, int* __restrict__ pos,
                         int2* __restrict__ pair) {
    int pass = blockIdx.x & (NPASS - 1);
    int e = (blockIdx.x >> 3) * blockDim.x + threadIdx.x;
    if (e >= N_ADJ) return;
    int r = rows[e];
    if ((unsigned)(r - pass * (N_UI / NPASS)) >= (unsigned)(N_UI / NPASS)) return;
    int slot = atomicAdd(&pos[r], 1);
    pair[slot] = make_int2(cols[e], __float_as_int(vals[e]));
}

// ---- per-user row offsets via binary search (interact_rows sorted) ----
__global__ void rowstart_kernel(const int* __restrict__ rows, int* __restrict__ rowstart) {
    int r = blockIdx.x * blockDim.x + threadIdx.x;
    if (r > N_USERS) return;
    int lo = 0, hi = N_INTERACT;
    while (lo < hi) {
        int mid = (lo + hi) >> 1;
        if (rows[mid] < r) lo = mid + 1; else hi = mid;
    }
    rowstart[r] = lo;
}

// ---- KG hop, fused gather + normalize + e_res(items only) + SNORM ----
// 4 groups x 16 lanes; 2-deep idx+row software pipeline per group
template <bool LAST>
__global__ void kg_hop(const int* __restrict__ rowptr, const int* __restrict__ tails,
                       const float* __restrict__ icnt, const float* __restrict__ Ain,
                       float* __restrict__ Aout, float* __restrict__ ER,
                       float* __restrict__ snorm) {
    int wid = (blockIdx.x * blockDim.x + threadIdx.x) >> 6;
    int lane = threadIdx.x & 63;
    int g = lane >> 4, gl = lane & 15;
    if (wid >= N_ENTITIES) return;
    int s = rowptr[wid], t = rowptr[wid + 1];
    float4 acc = {0.f, 0.f, 0.f, 0.f};
    int e = s + g;
    if (e < t) {
        int c = tails[e];
        float4 r = *(const float4*)(Ain + (size_t)c * D + gl * 4);
        int e2 = e + 4;
        int c2 = (e2 < t) ? tails[e2] : 0;
        while (true) {
            float4 r2 = {0.f, 0.f, 0.f, 0.f};
            if (e2 < t) r2 = *(const float4*)(Ain + (size_t)c2 * D + gl * 4);
            int e3 = e2 + 4;
            int c3 = (e3 < t) ? tails[e3] : 0;
            acc.x += r.x; acc.y += r.y; acc.z += r.z; acc.w += r.w;
            if (e2 >= t) break;
            e2 = e3; c2 = c3; r = r2;
        }
    }
    acc.x += __shfl_xor(acc.x, 16, 64); acc.x += __shfl_xor(acc.x, 32, 64);
    acc.y += __shfl_xor(acc.y, 16, 64); acc.y += __shfl_xor(acc.y, 32, 64);
    acc.z += __shfl_xor(acc.z, 16, 64); acc.z += __shfl_xor(acc.z, 32, 64);
    acc.w += __shfl_xor(acc.w, 16, 64); acc.w += __shfl_xor(acc.w, 32, 64);
    float ss = acc.x * acc.x + acc.y * acc.y + acc.z * acc.z + acc.w * acc.w;
    ss += __shfl_xor(ss, 1, 64); ss += __shfl_xor(ss, 2, 64);
    ss += __shfl_xor(ss, 4, 64); ss += __shfl_xor(ss, 8, 64);
    float nrm = fmaxf(sqrtf(ss), 1e-12f);
    float inv = 1.0f / nrm;
    if (g == 0) {
        size_t o = (size_t)wid * D + gl * 4;
        float4 ev = {acc.x * inv, acc.y * inv, acc.z * inv, acc.w * inv};
        *(float4*)(Aout + o) = ev;
        if (wid < N_ITEMS) {   // e_res only ever consumed as e_res[:N_ITEMS]
            float4 er = *(const float4*)(ER + o);
            er.x += ev.x; er.y += ev.y; er.z += ev.z; er.w += ev.w;
            *(float4*)(ER + o) = er;
            if (gl == 0) snorm[wid] = nrm * icnt[wid];
        }
    }
}

// ---- per-user pipeline: mean pass + 4 independent online-softmax chains ----
__global__ void user_hop(const float* __restrict__ E, const float* __restrict__ snorm,
                         const int* __restrict__ rowstart, const int* __restrict__ cols,
                         const float* __restrict__ vals, float* __restrict__ UR) {
    int wid = (blockIdx.x * blockDim.x + threadIdx.x) >> 6;
    int lane = threadIdx.x & 63;
    int g = lane >> 4, gl = lane & 15;
    if (wid >= N_USERS) return;
    int s = rowstart[wid], t = rowstart[wid + 1];

    // pass A: user_mean (weighted), pipelined gather
    float4 mean = {0.f, 0.f, 0.f, 0.f};
    {
        int e = s + g;
        if (e < t) {
            int c = cols[e];
            float w = vals[e] * snorm[c];
            float4 r = *(const float4*)(E + (size_t)c * D + gl * 4);
            int e2 = e + 4;
            while (true) {
                float w2 = 0.f; float4 r2 = {0.f, 0.f, 0.f, 0.f};
                bool more = (e2 < t);
                if (more) {
                    int c2 = cols[e2];
                    w2 = vals[e2] * snorm[c2];
                    r2 = *(const float4*)(E + (size_t)c2 * D + gl * 4);
                }
                mean.x += w * r.x; mean.y += w * r.y;
                mean.z += w * r.z; mean.w += w * r.w;
                if (!more) break;
                w = w2; r = r2; e2 += 4;
            }
        }
    }
    mean.x += __shfl_xor(mean.x, 16, 64); mean.x += __shfl_xor(mean.x, 32, 64);
    mean.y += __shfl_xor(mean.y, 16, 64); mean.y += __shfl_xor(mean.y, 32, 64);
    mean.z += __shfl_xor(mean.z, 16, 64); mean.z += __shfl_xor(mean.z, 32, 64);
    mean.w += __shfl_xor(mean.w, 16, 64); mean.w += __shfl_xor(mean.w, 32, 64);

    // pass B: per-group online softmax, loads prefetched one edge ahead
    float m = -INFINITY, denom = 0.f;
    float4 acc = {0.f, 0.f, 0.f, 0.f};
    {
        int e = s + g;
        if (e < t) {
            int c = cols[e];
            float sn = snorm[c];
            float4 r = *(const float4*)(E + (size_t)c * D + gl * 4);
            int e2 = e + 4;
            while (true) {
                float sn2 = 0.f; float4 r2 = {0.f, 0.f, 0.f, 0.f};
                bool more = (e2 < t);
                if (more) {
                    int c2 = cols[e2];
                    sn2 = snorm[c2];
                    r2 = *(const float4*)(E + (size_t)c2 * D + gl * 4);
                }
                float4 il = {sn * r.x, sn * r.y, sn * r.z, sn * r.w};
                float dx = il.x - mean.x + EPS_PD;
                float dy = il.y - mean.y + EPS_PD;
                float dz = il.z - mean.z + EPS_PD;
                float dw = il.w - mean.w + EPS_PD;
                float ssl = dx * dx + dy * dy + dz * dz + dw * dw;
                ssl += __shfl_xor(ssl, 1, 64); ssl += __shfl_xor(ssl, 2, 64);
                ssl += __shfl_xor(ssl, 4, 64); ssl += __shfl_xor(ssl, 8, 64);
                float sc = sqrtf(ssl) * INV_TEMP;
                float m_new = fmaxf(m, sc);
                float scale = __expf(m - m_new);
                float ex = __expf(sc - m_new);
                denom = denom * scale + ex;
                acc.x = acc.x * scale + ex * il.x;
                acc.y = acc.y * scale + ex * il.y;
                acc.z = acc.z * scale + ex * il.z;
                acc.w = acc.w * scale + ex * il.w;
                m = m_new;
                if (!more) break;
                sn = sn2; r = r2; e2 += 4;
            }
        }
    }
    // merge 4 group states
    float mg = fmaxf(m, __shfl_xor(m, 16, 64));
    mg = fmaxf(mg, __shfl_xor(mg, 32, 64));
    float scl = __expf(fmaxf(m - mg, -88.0f));   // fmax eats NaN from (-inf)-(-inf)
    denom *= scl;
    acc.x *= scl; acc.y *= scl; acc.z *= scl; acc.w *= scl;
    denom += __shfl_xor(denom, 16, 64); denom += __shfl_xor(denom, 32, 64);
    acc.x += __shfl_xor(acc.x, 16, 64); acc.x += __shfl_xor(acc.x, 32, 64);
    acc.y += __shfl_xor(acc.y, 16, 64); acc.y += __shfl_xor(acc.y, 32, 64);
    acc.z += __shfl_xor(acc.z, 16, 64); acc.z += __shfl_xor(acc.z, 32, 64);
    acc.w += __shfl_xor(acc.w, 16, 64); acc.w += __shfl_xor(acc.w, 32, 64);
    float invd = denom > 0.f ? 1.0f / denom : 0.f;
    acc.x *= invd; acc.y *= invd; acc.z *= invd; acc.w *= invd;
    float ss = acc.x * acc.x + acc.y * acc.y + acc.z * acc.z + acc.w * acc.w;
    ss += __shfl_xor(ss, 1, 64); ss += __shfl_xor(ss, 2, 64);
    ss += __shfl_xor(ss, 4, 64); ss += __shfl_xor(ss, 8, 64);
    float inv = 1.0f / fmaxf(sqrtf(ss), 1e-12f);
    if (g == 0) {
        size_t o = (size_t)wid * D + gl * 4;
        float4 u = *(const float4*)(UR + o);
        u.x += acc.x * inv; u.y += acc.y * inv; u.z += acc.z * inv; u.w += acc.w * inv;
        *(float4*)(UR + o) = u;
    }
}

// ---- adj gather SpMM; x rows come from split (U | I) base pointers ----
// MODE 0: Y = adj@x; out = x + Y     MODE 1: out = (out + adj@x) / 3
__device__ __forceinline__ const float* xrow(const float* U, const float* I, int c) {
    return (c < N_USERS) ? (U + (size_t)c * D) : (I + (size_t)(c - N_USERS) * D);
}

template <int MODE>
__global__ void adj_spmm(const int* __restrict__ rowptr, const int2* __restrict__ pair,
                         const float* __restrict__ XU, const float* __restrict__ XI,
                         float* __restrict__ Y, float* __restrict__ out) {
    int wid = (blockIdx.x * blockDim.x + threadIdx.x) >> 6;
    int lane = threadIdx.x & 63;
    int g = lane >> 4, gl = lane & 15;
    if (wid >= N_UI) return;
    int s = rowptr[wid], t = rowptr[wid + 1];
    float4 acc = {0.f, 0.f, 0.f, 0.f};
    int e = s + g;
    if (e < t) {
        int2 p = pair[e];
        float4 r = *(const float4*)(xrow(XU, XI, p.x) + gl * 4);
        int e2 = e + 4;
        int2 p2 = (e2 < t) ? pair[e2] : make_int2(0, 0);
        while (true) {
            float4 r2 = {0.f, 0.f, 0.f, 0.f};
            if (e2 < t) r2 = *(const float4*)(xrow(XU, XI, p2.x) + gl * 4);
            int e3 = e2 + 4;
            int2 p3 = (e3 < t) ? pair[e3] : make_int2(0, 0);
            float v = __int_as_float(p.y);
            acc.x += v * r.x; acc.y += v * r.y; acc.z += v * r.z; acc.w += v * r.w;
            if (e2 >= t) break;
            e2 = e3; p = p2; p2 = p3; r = r2;
        }
    }
    acc.x += __shfl_xor(acc.x, 16, 64); acc.x += __shfl_xor(acc.x, 32, 64);
    acc.y += __shfl_xor(acc.y, 16, 64); acc.y += __shfl_xor(acc.y, 32, 64);
    acc.z += __shfl_xor(acc.z, 16, 64); acc.z += __shfl_xor(acc.z, 32, 64);
    acc.w += __shfl_xor(acc.w, 16, 64); acc.w += __shfl_xor(acc.w, 32, 64);
    if (g == 0) {
        size_t o = (size_t)wid * D + gl * 4;
        if (MODE == 0) {
            *(float4*)(Y + o) = acc;
            const float4 xa = *(const float4*)(xrow(XU, XI, wid) + gl * 4);
            float4 ov = {xa.x + acc.x, xa.y + acc.y, xa.z + acc.z, xa.w + acc.w};
            *(float4*)(out + o) = ov;
        } else {
            float4 ov = *(const float4*)(out + o);
            ov.x = (ov.x + acc.x) * (1.0f / 3.0f);
            ov.y = (ov.y + acc.y) * (1.0f / 3.0f);
            ov.z = (ov.z + acc.z) * (1.0f / 3.0f);
            ov.w = (ov.w + acc.w) * (1.0f / 3.0f);
            *(float4*)(out + o) = ov;
        }
    }
}

extern "C" void kernel_launch(void* const* d_in, const int* in_sizes, int n_in,
                              void* d_out, int out_size, void* d_ws, size_t ws_size,
                              hipStream_t stream) {
    const float* all_embed     = (const float*)d_in[0];
    const float* interact_vals = (const float*)d_in[1];
    const float* adj_vals      = (const float*)d_in[2];
    const int*   edge_index    = (const int*)d_in[3];
    // d_in[4] = edge_type (unused)
    const int*   interact_rows = (const int*)d_in[5];
    const int*   interact_cols = (const int*)d_in[6];
    const int*   adj_rows      = (const int*)d_in[7];
    const int*   adj_cols      = (const int*)d_in[8];
    float* out = (float*)d_out;

    const size_t entN = (size_t)N_ENTITIES * D;   // 5,120,000
    const size_t usrN = (size_t)N_USERS * D;      // 3,200,000
    const size_t itmN = (size_t)N_ITEMS * D;      // 1,920,000

    float* ws    = (float*)d_ws;
    float* UR    = ws;                  // u_res (x users part)
    float* A0    = UR + usrN;           // entity ping / later x1
    float* A1    = A0 + entN;           // entity pong / later adj-CSR overlay
    float* ER    = A1 + entN;           // e_res, items only (itmN)
    float* ICNT  = ER + itmN;
    float* SNORM = ICNT + N_ENTITIES;   // N_ITEMS
    int* KG_CNT    = (int*)(SNORM + N_ITEMS);
    int* KG_ROWPTR = KG_CNT + N_ENTITIES;          // N_ENTITIES+1 (+pad)
    int* KG_POS    = KG_ROWPTR + N_ENTITIES + 2;
    int* KG_TAIL   = KG_POS + N_ENTITIES;          // N_KG_EDGES
    int* ROWSTART  = KG_TAIL + N_KG_EDGES;         // N_USERS+1

    // adj CSR overlaid on A1 (A1 dead after kg_hop hop 2 reads it)
    int*  ADJ_CNT    = (int*)A1;
    int*  ADJ_ROWPTR = ADJ_CNT + N_UI;             // N_UI+1 (+pad to even)
    int*  ADJ_POS    = ADJ_ROWPTR + N_UI + 2;
    int2* ADJ_PAIR   = (int2*)(ADJ_POS + N_UI);    // 8B-aligned (even word offset)

    // ---- KG CSR build + init ----
    hipMemsetAsync(KG_CNT, 0, N_ENTITIES * sizeof(int), stream);
    hist_kernel<<<(N_KG_EDGES + 255) / 256, 256, 0, stream>>>(edge_index, KG_CNT, N_KG_EDGES);
    icnt_kernel<<<(N_ENTITIES + 255) / 256, 256, 0, stream>>>(KG_CNT, ICNT);
    scan_kernel<<<1, SCAN_T, 0, stream>>>(KG_CNT, KG_ROWPTR, KG_POS, N_ENTITIES);
    kg_fill<<<NPASS * ((N_KG_EDGES + 255) / 256), 256, 0, stream>>>(edge_index, KG_POS, KG_TAIL);
    rowstart_kernel<<<(N_USERS + 256) / 256, 256, 0, stream>>>(interact_rows, ROWSTART);

    hipMemcpyAsync(UR, all_embed, usrN * sizeof(float), hipMemcpyDeviceToDevice, stream);
    hipMemcpyAsync(A0, all_embed + usrN, entN * sizeof(float), hipMemcpyDeviceToDevice, stream);
    hipMemcpyAsync(ER, all_embed + usrN, itmN * sizeof(float), hipMemcpyDeviceToDevice, stream);

    // ---- KG hops ----
    kg_hop<false><<<N_ENTITIES / 4, 256, 0, stream>>>(KG_ROWPTR, KG_TAIL, ICNT, A0, A1, ER, SNORM);
    user_hop<<<N_USERS / 4, 256, 0, stream>>>(A1, SNORM, ROWSTART, interact_cols,
                                              interact_vals, UR);
    kg_hop<true><<<N_ENTITIES / 4, 256, 0, stream>>>(KG_ROWPTR, KG_TAIL, ICNT, A1, A0, ER, SNORM);

    // ---- adj CSR build into A1 (now dead) ----
    hipMemsetAsync(ADJ_CNT, 0, N_UI * sizeof(int), stream);
    hist_kernel<<<(N_ADJ + 255) / 256, 256, 0, stream>>>(adj_rows, ADJ_CNT, N_ADJ);
    scan_kernel<<<1, SCAN_T, 0, stream>>>(ADJ_CNT, ADJ_ROWPTR, ADJ_POS, N_UI);
    adj_fill<<<NPASS * ((N_ADJ + 255) / 256), 256, 0, stream>>>(adj_rows, adj_cols, adj_vals,
                                                                ADJ_POS, ADJ_PAIR);

    user_hop<<<N_USERS / 4, 256, 0, stream>>>(A0, SNORM, ROWSTART, interact_cols,
                                              interact_vals, UR);

    // ---- LGCN: x = (UR | ER) split; x1 = adj@x -> A0; out = x + x1; out = (out + adj@x1)/3 ----
    adj_spmm<0><<<N_UI / 4, 256, 0, stream>>>(ADJ_ROWPTR, ADJ_PAIR, UR, ER, A0, out);
    adj_spmm<1><<<N_UI / 4, 256, 0, stream>>>(ADJ_ROWPTR, ADJ_PAIR, A0, A0 + usrN,
                                              nullptr, out);
}